// Round 1
// baseline (893.366 us; speedup 1.0000x reference)
//
#include <hip/hip_runtime.h>

#define HID 64
#define TPB 256

__device__ __forceinline__ void grid_feat(const float4* __restrict__ t, int res,
                                          float u, float v, float* f) {
    float r = (float)res;
    float sx = u * r;
    float sy = v * r;
    int x0 = (int)sx;               // truncation; sx,sy >= 0, matches astype(int32)
    int y0 = (int)sy;
    float wx = sx - (float)x0;
    float wy = sy - (float)y0;
    int x1 = min(x0 + 1, res);
    int y1 = min(y0 + 1, res);
    // NOTE: reference indexes with stride = res (not res+1); rows fit since
    // table has (res+1)^2 rows and max index = res*res + res.
    float4 v00 = t[y0 * res + x0];
    float4 v10 = t[y0 * res + x1];
    float4 v01 = t[y1 * res + x0];
    float4 v11 = t[y1 * res + x1];
    float omx = 1.0f - wx;
    float omy = 1.0f - wy;
    float tx, bx;
    tx = v00.x * omx + v10.x * wx;  bx = v01.x * omx + v11.x * wx;  f[0] = tx * omy + bx * wy;
    tx = v00.y * omx + v10.y * wx;  bx = v01.y * omx + v11.y * wx;  f[1] = tx * omy + bx * wy;
    tx = v00.z * omx + v10.z * wx;  bx = v01.z * omx + v11.z * wx;  f[2] = tx * omy + bx * wy;
    tx = v00.w * omx + v10.w * wx;  bx = v01.w * omx + v11.w * wx;  f[3] = tx * omy + bx * wy;
}

__global__ __launch_bounds__(TPB) void dgn_kernel(
    const float*  __restrict__ x,     // N x 3
    const float4* __restrict__ emb0,  // 513^2 rows of 4
    const float4* __restrict__ emb1,  // 265^2 rows of 4
    const float4* __restrict__ emb2,  // 17^2  rows of 4
    const float*  __restrict__ w1,    // 13 x 64
    const float*  __restrict__ b1,    // 64
    const float*  __restrict__ w2,    // 64 x 64
    const float*  __restrict__ b2,    // 64
    const float*  __restrict__ w3,    // 64 x 3
    const float*  __restrict__ b3,    // 3
    float*        __restrict__ out,   // N x 3
    int n)
{
    // h1 staged per-thread in LDS so the layer-2 k-loop can index it
    // dynamically without register-array scratch spills.
    // Layout h1[k*TPB + tid]: lane-linear -> 2 lanes/bank (free on gfx950).
    __shared__ float lds_h1[HID * TPB];

    int tid = threadIdx.x;
    int i = blockIdx.x * TPB + tid;
    if (i >= n) return;

    float idf = x[3 * i + 0];
    float u   = x[3 * i + 1];
    float v   = x[3 * i + 2];

    float e[13];
    e[0] = idf;
    grid_feat(emb0, 512, u, v, &e[1]);
    grid_feat(emb1, 264, u, v, &e[5]);
    grid_feat(emb2, 16,  u, v, &e[9]);

    // ---- layer 1: 13 -> 64, relu. Weights wave-uniform -> scalar loads. ----
    float h[HID];
    #pragma unroll
    for (int j = 0; j < HID; ++j) h[j] = b1[j];
    #pragma unroll
    for (int k = 0; k < 13; ++k) {
        float ek = e[k];
        const float* wr = w1 + k * HID;
        #pragma unroll
        for (int j = 0; j < HID; ++j) h[j] = fmaf(ek, wr[j], h[j]);
    }
    #pragma unroll
    for (int j = 0; j < HID; ++j) {
        lds_h1[j * TPB + tid] = fmaxf(h[j], 0.0f);
    }

    // ---- layer 2: 64 -> 64, relu. ----
    float h2[HID];
    #pragma unroll
    for (int j = 0; j < HID; ++j) h2[j] = b2[j];
    #pragma unroll 4
    for (int k = 0; k < HID; ++k) {
        float hk = lds_h1[k * TPB + tid];
        const float* wr = w2 + k * HID;
        #pragma unroll
        for (int j = 0; j < HID; ++j) h2[j] = fmaf(hk, wr[j], h2[j]);
    }

    // ---- layer 3: 64 -> 3 ----
    float o0 = b3[0], o1 = b3[1], o2 = b3[2];
    #pragma unroll
    for (int k = 0; k < HID; ++k) {
        float hk = fmaxf(h2[k], 0.0f);
        o0 = fmaf(hk, w3[3 * k + 0], o0);
        o1 = fmaf(hk, w3[3 * k + 1], o1);
        o2 = fmaf(hk, w3[3 * k + 2], o2);
    }

    out[3 * i + 0] = o0;
    out[3 * i + 1] = o1;
    out[3 * i + 2] = o2;
}

extern "C" void kernel_launch(void* const* d_in, const int* in_sizes, int n_in,
                              void* d_out, int out_size, void* d_ws, size_t ws_size,
                              hipStream_t stream) {
    const float*  x    = (const float*)  d_in[0];
    const float4* emb0 = (const float4*) d_in[1];
    const float4* emb1 = (const float4*) d_in[2];
    const float4* emb2 = (const float4*) d_in[3];
    const float*  w1   = (const float*)  d_in[4];
    const float*  b1   = (const float*)  d_in[5];
    const float*  w2   = (const float*)  d_in[6];
    const float*  b2   = (const float*)  d_in[7];
    const float*  w3   = (const float*)  d_in[8];
    const float*  b3   = (const float*)  d_in[9];
    float* out = (float*)d_out;

    int n = in_sizes[0] / 3;
    int grid = (n + TPB - 1) / TPB;
    dgn_kernel<<<grid, TPB, 0, stream>>>(x, emb0, emb1, emb2,
                                         w1, b1, w2, b2, w3, b3, out, n);
}

// Round 2
// 298.937 us; speedup vs baseline: 2.9885x; 2.9885x over previous
//
#include <hip/hip_runtime.h>

typedef _Float16 half8 __attribute__((ext_vector_type(8)));
typedef _Float16 half4 __attribute__((ext_vector_type(4)));
typedef float floatx4 __attribute__((ext_vector_type(4)));

#define TPB 256

__device__ __forceinline__ void grid_feat(const float4* __restrict__ t, int res,
                                          float u, float v, float* f) {
    float r = (float)res;
    float sx = u * r;
    float sy = v * r;
    int x0 = (int)sx;               // truncation; sx,sy >= 0, matches astype(int32)
    int y0 = (int)sy;
    float wx = sx - (float)x0;
    float wy = sy - (float)y0;
    int x1 = min(x0 + 1, res);
    int y1 = min(y0 + 1, res);
    // reference indexes with stride = res (not res+1)
    float4 v00 = t[y0 * res + x0];
    float4 v10 = t[y0 * res + x1];
    float4 v01 = t[y1 * res + x0];
    float4 v11 = t[y1 * res + x1];
    float omx = 1.0f - wx;
    float omy = 1.0f - wy;
    float tx, bx;
    tx = v00.x * omx + v10.x * wx;  bx = v01.x * omx + v11.x * wx;  f[0] = tx * omy + bx * wy;
    tx = v00.y * omx + v10.y * wx;  bx = v01.y * omx + v11.y * wx;  f[1] = tx * omy + bx * wy;
    tx = v00.z * omx + v10.z * wx;  bx = v01.z * omx + v11.z * wx;  f[2] = tx * omy + bx * wy;
    tx = v00.w * omx + v10.w * wx;  bx = v01.w * omx + v11.w * wx;  f[3] = tx * omy + bx * wy;
}

// Per-wave fused MFMA pipeline. Each wave processes 64 points per tile-iter.
// LDS: one private 64-row x 64-half (128B) buffer per wave, XOR-chunk-swizzled;
// reused in place for E (chunks 0-1), then h1, then h2 (same rows, per m-tile).
// Hidden dim stored permuted: sigma(h) = 4*(h&15) + (h>>4), so the MFMA C-layout
// (4 regs = 4 rows, col = l15) packs into contiguous half4 b64 writes. W2/W3
// register fragments are built with sigma^{-1}-permuted rows to compensate.
__global__ __launch_bounds__(TPB, 3) void dgn_mfma(
    const float*  __restrict__ x,
    const float4* __restrict__ emb0,
    const float4* __restrict__ emb1,
    const float4* __restrict__ emb2,
    const float*  __restrict__ w1, const float* __restrict__ b1,
    const float*  __restrict__ w2, const float* __restrict__ b2,
    const float*  __restrict__ w3, const float* __restrict__ b3,
    float*        __restrict__ out, int npts)
{
    __shared__ __align__(16) _Float16 smem[4 * 4096];   // 4 waves * 8KB

    const int tid  = threadIdx.x;
    const int lane = tid & 63;
    const int wv   = tid >> 6;
    const int l15  = lane & 15;
    const int quad = lane >> 4;
    _Float16* buf = smem + wv * 4096;

    // ---- persistent per-lane weight fragments (B-layout: k = quad*8+j, n = l15) ----
    half8 w1f[4];
    #pragma unroll
    for (int nt = 0; nt < 4; ++nt) {
        #pragma unroll
        for (int j = 0; j < 8; ++j) {
            int k = quad * 8 + j;                       // layer1 K=32, real k<13
            w1f[nt][j] = (k < 13) ? (_Float16)w1[k * 64 + nt * 16 + l15] : (_Float16)0.0f;
        }
    }
    float b1v[4], b2v[4];
    #pragma unroll
    for (int nt = 0; nt < 4; ++nt) {
        b1v[nt] = b1[nt * 16 + l15];
        b2v[nt] = b2[nt * 16 + l15];
    }
    half8 w2f[4][2];
    #pragma unroll
    for (int nt = 0; nt < 4; ++nt) {
        #pragma unroll
        for (int ks = 0; ks < 2; ++ks) {
            #pragma unroll
            for (int j = 0; j < 8; ++j) {
                int s  = ks * 32 + quad * 8 + j;        // sigma-space k
                int oh = ((s & 3) << 4) | (s >> 2);     // original hidden index
                w2f[nt][ks][j] = (_Float16)w2[oh * 64 + nt * 16 + l15];
            }
        }
    }
    // layer3 transposed: A = W3^T (rows = out channel c = l15, zero-padded c>=3)
    half8 w3f[2];
    #pragma unroll
    for (int ks = 0; ks < 2; ++ks) {
        #pragma unroll
        for (int j = 0; j < 8; ++j) {
            int s  = ks * 32 + quad * 8 + j;
            int oh = ((s & 3) << 4) | (s >> 2);
            w3f[ks][j] = (l15 < 3) ? (_Float16)w3[oh * 3 + l15] : (_Float16)0.0f;
        }
    }
    const float bias3_0 = b3[0], bias3_1 = b3[1], bias3_2 = b3[2];
    const float qsel = (quad == 0) ? 1.0f : 0.0f;       // D3' rows c=quad*4+r; only quad0 real

    const int ntiles = npts >> 8;                       // 256 points per block-tile
    for (int tile = blockIdx.x; tile < ntiles; tile += gridDim.x) {
        const int p = (tile << 8) + (wv << 6) + lane;

        // ---- per-lane fp32 embedding ----
        float idf = x[3 * p + 0];
        float uu  = x[3 * p + 1];
        float vv  = x[3 * p + 2];
        float f[12];
        grid_feat(emb0, 512, uu, vv, f);
        grid_feat(emb1, 264, uu, vv, f + 4);
        grid_feat(emb2, 16,  uu, vv, f + 8);

        // ---- E row (16 real halves, K padded to 32 via zero A-frags for quad>=2) ----
        half8 e0 = { (_Float16)idf,   (_Float16)f[0], (_Float16)f[1], (_Float16)f[2],
                     (_Float16)f[3],  (_Float16)f[4], (_Float16)f[5], (_Float16)f[6] };
        half8 e1 = { (_Float16)f[7],  (_Float16)f[8], (_Float16)f[9], (_Float16)f[10],
                     (_Float16)f[11], (_Float16)0.0f, (_Float16)0.0f, (_Float16)0.0f };
        {
            const int m = lane;
            *(half8*)&buf[m * 64 + ((0 ^ (m & 7)) * 8)] = e0;
            *(half8*)&buf[m * 64 + ((1 ^ (m & 7)) * 8)] = e1;
        }

        // ---- layer 1 (MFMA, K=32; bias in C-init), h1 -> LDS sigma-packed ----
        #pragma unroll
        for (int mt = 0; mt < 4; ++mt) {
            const int row = mt * 16 + l15;
            half8 ea = { (_Float16)0.0f, (_Float16)0.0f, (_Float16)0.0f, (_Float16)0.0f,
                         (_Float16)0.0f, (_Float16)0.0f, (_Float16)0.0f, (_Float16)0.0f };
            if (quad < 2)
                ea = *(const half8*)&buf[row * 64 + ((quad ^ (row & 7)) * 8)];
            floatx4 acc[4];
            #pragma unroll
            for (int nt = 0; nt < 4; ++nt) {
                acc[nt] = (floatx4){ b1v[nt], b1v[nt], b1v[nt], b1v[nt] };
                acc[nt] = __builtin_amdgcn_mfma_f32_16x16x32_f16(ea, w1f[nt], acc[nt], 0, 0, 0);
            }
            // C-layout: lane holds rows p=mt*16+quad*4+r, col n1=nt*16+l15.
            // sigma packs the 4 nt-values contiguously -> one b64 per (mt,r).
            #pragma unroll
            for (int r = 0; r < 4; ++r) {
                half4 hv = { (_Float16)fmaxf(acc[0][r], 0.0f),
                             (_Float16)fmaxf(acc[1][r], 0.0f),
                             (_Float16)fmaxf(acc[2][r], 0.0f),
                             (_Float16)fmaxf(acc[3][r], 0.0f) };
                const int prow = mt * 16 + quad * 4 + r;
                const int effc = (l15 >> 1) ^ (prow & 7);
                *(half4*)&buf[prow * 64 + effc * 8 + (l15 & 1) * 4] = hv;
            }
        }

        // ---- layer 2 (K=64, 2 ksteps) + layer 3 (transposed), per m-tile ----
        #pragma unroll
        for (int mt = 0; mt < 4; ++mt) {
            const int row = mt * 16 + l15;
            floatx4 acc[4];
            #pragma unroll
            for (int nt = 0; nt < 4; ++nt)
                acc[nt] = (floatx4){ b2v[nt], b2v[nt], b2v[nt], b2v[nt] };
            #pragma unroll
            for (int ks = 0; ks < 2; ++ks) {
                half8 a2 = *(const half8*)&buf[row * 64 + (((ks * 4 + quad) ^ (row & 7)) * 8)];
                #pragma unroll
                for (int nt = 0; nt < 4; ++nt)
                    acc[nt] = __builtin_amdgcn_mfma_f32_16x16x32_f16(a2, w2f[nt][ks], acc[nt], 0, 0, 0);
            }
            // h2 overwrites the (now-dead) h1 rows of this m-tile, sigma-packed.
            #pragma unroll
            for (int r = 0; r < 4; ++r) {
                half4 hv = { (_Float16)fmaxf(acc[0][r], 0.0f),
                             (_Float16)fmaxf(acc[1][r], 0.0f),
                             (_Float16)fmaxf(acc[2][r], 0.0f),
                             (_Float16)fmaxf(acc[3][r], 0.0f) };
                const int prow = mt * 16 + quad * 4 + r;
                const int effc = (l15 >> 1) ^ (prow & 7);
                *(half4*)&buf[prow * 64 + effc * 8 + (l15 & 1) * 4] = hv;
            }
            // layer 3: D3'[c][p] = sum_h W3[h][c] * h2[p][h]; A=W3^T frags, B=h2 reads
            floatx4 acc3 = (floatx4){ qsel * bias3_0, qsel * bias3_1, qsel * bias3_2, 0.0f };
            #pragma unroll
            for (int ks = 0; ks < 2; ++ks) {
                half8 bfr = *(const half8*)&buf[row * 64 + (((ks * 4 + quad) ^ (row & 7)) * 8)];
                acc3 = __builtin_amdgcn_mfma_f32_16x16x32_f16(w3f[ks], bfr, acc3, 0, 0, 0);
            }
            // D3' C-layout: row (=channel c) = quad*4+r, col (=point) = l15.
            if (quad == 0) {
                const int P = (tile << 8) + (wv << 6) + mt * 16 + l15;
                out[3 * P + 0] = acc3[0];
                out[3 * P + 1] = acc3[1];
                out[3 * P + 2] = acc3[2];
            }
        }
    }
}

extern "C" void kernel_launch(void* const* d_in, const int* in_sizes, int n_in,
                              void* d_out, int out_size, void* d_ws, size_t ws_size,
                              hipStream_t stream) {
    const float*  x    = (const float*)  d_in[0];
    const float4* emb0 = (const float4*) d_in[1];
    const float4* emb1 = (const float4*) d_in[2];
    const float4* emb2 = (const float4*) d_in[3];
    const float*  w1   = (const float*)  d_in[4];
    const float*  b1   = (const float*)  d_in[5];
    const float*  w2   = (const float*)  d_in[6];
    const float*  b2   = (const float*)  d_in[7];
    const float*  w3   = (const float*)  d_in[8];
    const float*  b3   = (const float*)  d_in[9];
    float* out = (float*)d_out;

    int npts = in_sizes[0] / 3;
    int grid = 768;                                     // 256 CUs * 3 blocks/CU resident
    dgn_mfma<<<grid, TPB, 0, stream>>>(x, emb0, emb1, emb2,
                                       w1, b1, w2, b2, w3, b3, out, npts);
}